// Round 14
// baseline (277.119 us; speedup 1.0000x reference)
//
#include <hip/hip_runtime.h>

#define B_ 2
#define L_ 2048
#define D_ 768
#define H_ 8
#define DK_ 64
#define DV_ 96
#define NPOS_ 32

typedef __attribute__((ext_vector_type(8))) __bf16 bf16x8;
typedef __attribute__((ext_vector_type(4))) __bf16 bf16x4;
typedef __attribute__((ext_vector_type(4))) float f32x4;

static __device__ __forceinline__ float bs2f(short s) {
    return (float)__builtin_bit_cast(__bf16, s);
}
static __device__ __forceinline__ short f2bs(float f) {
    return __builtin_bit_cast(short, (__bf16)f);
}

typedef __attribute__((address_space(1))) void gas_void;
typedef __attribute__((address_space(3))) void las_void;
static __device__ __forceinline__ void gload16(const short* g, char* l) {
    __builtin_amdgcn_global_load_lds((const gas_void*)g, (las_void*)l, 16, 0, 0);
}

// ---------------------------------------------------------------------------
// prep (fused with rmsnorm1): blocks 0..1055 transpose weights; block 1056
// builds sidx + VU/VS tables; blocks 1057.. do rmsnorm rows of x -> h1.
// ---------------------------------------------------------------------------
__global__ __launch_bounds__(256) void prep_kernel(
    const float* __restrict__ wq, const float* __restrict__ wk,
    const float* __restrict__ wv, const float* __restrict__ wo,
    const float* __restrict__ w1, const float* __restrict__ w2,
    const float* __restrict__ vparam, const float* __restrict__ uparam,
    const float* __restrict__ wpos,
    short* __restrict__ wqkvT, short* __restrict__ woT,
    short* __restrict__ w1T, short* __restrict__ w2T,
    unsigned char* __restrict__ sidx, float* __restrict__ VU, float* __restrict__ VS,
    const float* __restrict__ x, const float* __restrict__ n1w, short* __restrict__ h1)
{
    __shared__ short T[64][66];
    __shared__ float vw[H_ * NPOS_];
    __shared__ float uw[H_ * NPOS_];
    __shared__ float red[4];
    int blk = blockIdx.x, tid = threadIdx.x;
    if (blk < 1056) {
        const float* W; short* Wt; int K, N, bx, by;
        if (blk < 96)       { W = wq; Wt = wqkvT;              K = 768;  N = 512;  int b = blk;       bx = b % 8;  by = b / 8; }
        else if (blk < 192) { W = wk; Wt = wqkvT + 512 * 768;  K = 768;  N = 512;  int b = blk - 96;  bx = b % 8;  by = b / 8; }
        else if (blk < 336) { W = wv; Wt = wqkvT + 1024 * 768; K = 768;  N = 768;  int b = blk - 192; bx = b % 12; by = b / 12; }
        else if (blk < 480) { W = wo; Wt = woT;                K = 768;  N = 768;  int b = blk - 336; bx = b % 12; by = b / 12; }
        else if (blk < 768) { W = w1; Wt = w1T;                K = 768;  N = 1536; int b = blk - 480; bx = b % 24; by = b / 24; }
        else                { W = w2; Wt = w2T;                K = 1536; N = 768;  int b = blk - 768; bx = b % 12; by = b / 12; }
        int n0 = bx << 6, k0 = by << 6;
        for (int idx = tid; idx < 4096; idx += 256) {
            int r = idx >> 6, c = idx & 63;
            T[c][r] = f2bs(W[(size_t)(k0 + r) * N + n0 + c]);
        }
        __syncthreads();
        for (int idx = tid; idx < 4096; idx += 256) {
            int r = idx >> 6, c = idx & 63;
            Wt[(size_t)(n0 + r) * K + k0 + c] = T[r][c];
        }
    } else if (blk == 1056) {
        float pr = expf(logf((L_ + 1) / 2.0f) / (NPOS_ / 2));
        if (tid < 16) vw[tid] = powf(pr, (float)(tid + 1));   // cw table, once
        __syncthreads();
        for (int idx = tid; idx < 4095; idx += 256) {
            int d = idx - 2047;
            int ad = d < 0 ? -d : d;
            int c = 0;
#pragma unroll
            for (int m = 0; m < 16; ++m)
                if (vw[m] < (float)ad) c++;
            sidx[idx] = (unsigned char)(d > 0 ? c : (d < 0 ? 17 + c : 34));
        }
        __syncthreads();
        {
            int h = tid >> 5, n = tid & 31;
            float av = 0.f, au = 0.f;
            for (int d = 0; d < DK_; ++d) {
                float wp = wpos[(h * DK_ + d) * NPOS_ + n];
                av += vparam[h * DK_ + d] * wp;
                au += uparam[h * DK_ + d] * wp;
            }
            vw[tid] = av;
            uw[tid] = au;
        }
        __syncthreads();
        if (tid < H_ * 17) {
            int h = tid / 17, m = tid % 17;
            float su = 0.f, ss = 0.f;
            for (int t2 = m; t2 < 16; ++t2) {
                su += vw[h * NPOS_ + t2] - uw[h * NPOS_ + t2];
                ss += vw[h * NPOS_ + 16 + t2] - uw[h * NPOS_ + 16 + t2];
            }
            VU[h * 17 + m] = su * 0.125f;
            VS[h * 17 + m] = ss * 0.125f;
        }
    } else {
        int row = blk - 1057;
        const float* xr = x + (size_t)row * D_;
        float ss = 0.f;
        for (int c = tid; c < D_; c += 256) { float f = xr[c]; ss += f * f; }
        for (int msk = 1; msk < 64; msk <<= 1) ss += __shfl_xor(ss, msk);
        if ((tid & 63) == 0) red[tid >> 6] = ss;
        __syncthreads();
        float tot = red[0] + red[1] + red[2] + red[3];
        float sc = rsqrtf(tot * (1.f / D_) + 1e-5f);
        for (int c = tid; c < D_; c += 256)
            h1[(size_t)row * D_ + c] = f2bs(xr[c] * sc * n1w[c]);
    }
}

// ---------------------------------------------------------------------------
// RMSNorm (row of 768), fp32 in, bf16 out (second norm only)
// ---------------------------------------------------------------------------
__global__ __launch_bounds__(256) void rmsnorm_kernel(
    const float* __restrict__ x, const float* __restrict__ wgt, short* __restrict__ out)
{
    int row = blockIdx.x, tid = threadIdx.x;
    __shared__ float red[4];
    const float* xr = x + (size_t)row * D_;
    float ss = 0.f;
    for (int c = tid; c < D_; c += 256) { float f = xr[c]; ss += f * f; }
    for (int msk = 1; msk < 64; msk <<= 1) ss += __shfl_xor(ss, msk);
    if ((tid & 63) == 0) red[tid >> 6] = ss;
    __syncthreads();
    float tot = red[0] + red[1] + red[2] + red[3];
    float sc = rsqrtf(tot * (1.f / D_) + 1e-5f);
    for (int c = tid; c < D_; c += 256)
        out[(size_t)row * D_ + c] = f2bs(xr[c] * sc * wgt[c]);
}

// ---------------------------------------------------------------------------
// gemmx v2: BK=32, TRIPLE-buffered global_load_lds staging with COUNTED
// vmcnt + raw s_barrier (T3/T4 minimum): the main loop never drains vmcnt
// to 0, so the next-buffer loads stay in flight across the barrier (the
// m97-structure's ~20% drain stall was the K=768 small-shape killer).
// Per iter: vmcnt(2) [current buffer's 2 loads = oldest] -> s_barrier ->
// issue stage(t+2) -> ds_read+MFMA on buf[t]. stage(t+2) overwrites
// buf[(t-1)%3], whose readers all passed the barrier (safe).
// Loads/stage/wave uniform = 2 (A + B; BN=64 upper waves issue duplicate
// identical B loads -> benign same-data write, uniform vmcnt accounting).
// Swizzle: slot(r,c) holds k-chunk (c ^ ((r>>1)&3)); read chunk
// quad ^ ((r>>1)&3) -> round-trip exact, uniform 8 accesses/bank.
// LDS: 3 x (8K + BN*64) = 48K (BN=128, 3 blk/CU) / 36K (BN=64, 4 blk/CU).
// K-accumulation order identical to the r13 kernel (bitwise same results).
// ---------------------------------------------------------------------------
template<int BN>
__global__ __launch_bounds__(512, 4) void gemmx(
    const short* __restrict__ A, const short* __restrict__ Bt,
    const float* __restrict__ bias, const float* __restrict__ uadd,
    const float* __restrict__ resid, void* __restrict__ outp,
    int M, int N, int K, int act, int out_f32)
{
    constexpr int BUF = 8192 + BN * 64;            // A 8KB + B BN*64 bytes
    __shared__ __align__(16) char ldsb[3 * BUF];
    int tid = threadIdx.x;
    int w = tid >> 6, lane = tid & 63, quad = lane >> 4, t = lane & 15;
    int wm = (w >> 1) << 5;                        // 4 wave-rows of 32
    int wn = (w & 1) * (BN / 2);                   // 2 wave-cols
    int m0b = blockIdx.y << 7, n0b = blockIdx.x * BN;

    // staging maps: A chunk = tid (512 x 16B = 8KB); B chunk via bw
    int srowA = tid >> 2;
    int scA = ((tid & 3) ^ ((srowA >> 1) & 3)) << 3;
    const short* aSrc = A + (size_t)(m0b + srowA) * K + scA;
    int bw = (BN == 128) ? w : (w & 3);            // BN=64: waves 4-7 dup 0-3
    int pt = (bw << 6) + lane;
    int srowB = pt >> 2;
    int scB = ((pt & 3) ^ ((srowB >> 1) & 3)) << 3;
    const short* bSrc = Bt + (size_t)(n0b + srowB) * K + scB;
    int aOff = w << 10;                            // wave-uniform LDS bases
    int bOff = 8192 + (bw << 10);

    f32x4 acc[2][BN / 32] = {};
    int nIter = K >> 5;                            // BK=32

    // prologue: stage t0 -> buf0, t1 -> buf1 (4 loads outstanding / wave)
    gload16(aSrc, ldsb + aOff);
    gload16(bSrc, ldsb + bOff);
    gload16(aSrc + 32, ldsb + BUF + aOff);
    gload16(bSrc + 32, ldsb + BUF + bOff);

    char* p0 = ldsb;
    char* p1 = ldsb + BUF;
    char* p2 = ldsb + 2 * BUF;
    for (int it = 0; it < nIter; ++it) {
        if (it + 1 < nIter) {
            asm volatile("s_waitcnt vmcnt(2)" ::: "memory");
        } else {
            asm volatile("s_waitcnt vmcnt(0)" ::: "memory");
        }
        __builtin_amdgcn_s_barrier();
        int kn = (it + 2) << 5;
        if (kn < K) {
            gload16(aSrc + kn, p2 + aOff);
            gload16(bSrc + kn, p2 + bOff);
        }
        bf16x8 af[2], bf[BN / 32];
#pragma unroll
        for (int ms = 0; ms < 2; ++ms) {
            int R = wm + ms * 16 + t;
            af[ms] = *(const bf16x8*)(p0 + R * 64 + (((quad ^ (R >> 1)) & 3) << 4));
        }
#pragma unroll
        for (int ns = 0; ns < BN / 32; ++ns) {
            int R = wn + ns * 16 + t;
            bf[ns] = *(const bf16x8*)(p0 + 8192 + R * 64 + (((quad ^ (R >> 1)) & 3) << 4));
        }
#pragma unroll
        for (int ms = 0; ms < 2; ++ms)
#pragma unroll
            for (int ns = 0; ns < BN / 32; ++ns)
                acc[ms][ns] = __builtin_amdgcn_mfma_f32_16x16x32_bf16(af[ms], bf[ns], acc[ms][ns], 0, 0, 0);
        char* tmp = p0; p0 = p1; p1 = p2; p2 = tmp;
    }
#pragma unroll
    for (int ms = 0; ms < 2; ++ms)
#pragma unroll
        for (int ns = 0; ns < BN / 32; ++ns)
#pragma unroll
            for (int r = 0; r < 4; ++r) {
                int row = m0b + wm + ms * 16 + (quad << 2) + r;
                int col = n0b + wn + ns * 16 + t;
                float v2 = acc[ms][ns][r];
                if (uadd && col < 512) v2 = 0.125f * (v2 + uadd[col]);
                if (bias) v2 += bias[col];
                if (act == 1) v2 = 0.5f * v2 * (1.f + erff(v2 * 0.70710678118654752f));
                if (resid) v2 += resid[(size_t)row * N + col];
                if (out_f32) ((float*)outp)[(size_t)row * N + col] = v2;
                else ((short*)outp)[(size_t)row * N + col] = f2bs(v2);
            }
}

// ---------------------------------------------------------------------------
// qv: fused qsuf (blocks 0..511, 8 rows each) + fragment-linear vtrans
// (512..767) + fragment-linear ktrans (768..1023).
// qsuf: wpos slice lives in 64 VGPRs (thread-invariant); q read per-row
// straight from global as bf16x8; LDS only for qw/sU/sS reductions.
// vT: [bh][jt=32][f=dv*2+ks][lane=64][8]; frag[l=(q,t)][e] =
//     V[j0 + (e&3)*16 + ks*8 + q*2 + (e>>2)][dv*16+t].
// kT: [bh][jt=32][f=ct*2+half][lane=64][8]; frag[l=(q,t)][e] =
//     K[j0 + ct*16 + t][half*32 + q*8 + e]  (contiguous 16B per lane).
// ---------------------------------------------------------------------------
__global__ __launch_bounds__(256) void qv_kernel(
    const short* __restrict__ qkv, const float* __restrict__ wpos,
    const float* __restrict__ VU, const float* __restrict__ VS,
    float* __restrict__ Tg, short* __restrict__ vT, short* __restrict__ kT)
{
    __shared__ __align__(16) char arena[69696];
    int blk = blockIdx.x, tid = threadIdx.x;
    if (blk < 512) {
        float* qw = (float*)arena;              // 256
        float* sU = (float*)(arena + 1024);     // 136
        float* sS = (float*)(arena + 1568);     // 136
        int h = tid >> 5, n = tid & 31;
        float wlr[64];
#pragma unroll
        for (int d = 0; d < DK_; ++d)
            wlr[d] = wpos[(h * DK_ + d) * NPOS_ + n];
        int r0 = blk << 3;
        for (int rr = 0; rr < 8; ++rr) {
            int row = r0 + rr;
            const short* base = qkv + (size_t)row * 1792 + h * DK_;
            float acc = 0.f;
#pragma unroll
            for (int c8 = 0; c8 < 8; ++c8) {
                bf16x8 q8 = *(const bf16x8*)(base + (c8 << 3));
#pragma unroll
                for (int e = 0; e < 8; ++e)
                    acc += (float)q8[e] * wlr[(c8 << 3) + e];
            }
            qw[tid] = acc;
            __syncthreads();
            if (tid < 136) {
                int hh = tid / 17, m = tid % 17;
                float su = 0.f, ss = 0.f;
                for (int t2 = m; t2 < 16; ++t2) { su += qw[hh * NPOS_ + t2]; ss += qw[hh * NPOS_ + 16 + t2]; }
                sU[tid] = su + VU[tid];
                sS[tid] = ss + VS[tid];
            }
            __syncthreads();
            if (tid < 280) {
                int h2 = tid / 35, s = tid % 35;
                int m = s < 17 ? s : (s < 34 ? s - 17 : 0);
                float su = sU[h2 * 17 + m], ss = sS[h2 * 17 + m];
                Tg[(size_t)row * 280 + tid] = s < 17 ? su + ss : (s < 34 ? su - ss : su);
            }
        }
    } else if (blk < 768) {
        short* T = (short*)arena;   // [128][104]
        int vb = blk - 512;
        int bh = vb >> 4, b = bh >> 3, h = bh & 7;
        int j0 = (vb & 15) << 7;
#pragma unroll
        for (int it = 0; it < 6; ++it) {
            int idx = tid + (it << 8);
            int row = idx / 12, c8 = (idx % 12) << 3;
            *(bf16x8*)&T[row * 104 + c8] =
                *(const bf16x8*)&qkv[(size_t)(b * L_ + j0 + row) * 1792 + 1024 + h * DV_ + c8];
        }
        __syncthreads();
#pragma unroll
        for (int it = 0; it < 6; ++it) {
            int idx = tid + (it << 8);       // 0..1535 = sub*768 + f*64 + l
            int sub = idx / 768;
            int rem = idx - sub * 768;
            int f = rem >> 6, l = rem & 63;
            int dv = f >> 1, ks = f & 1;
            int q = l >> 4, t = l & 15;
            bf16x8 o;
#pragma unroll
            for (int e = 0; e < 8; ++e) {
                int jl = ((e & 3) << 4) + (ks << 3) + (q << 1) + (e >> 2);
                o[e] = __builtin_bit_cast(__bf16, T[(sub * 64 + jl) * 104 + dv * 16 + t]);
            }
            int jt = ((vb & 15) << 1) + sub;
            *(bf16x8*)&vT[((((size_t)bh * 32 + jt) * 12 + f) * 64 + l) * 8] = o;
        }
    } else {
        short* T = (short*)arena;   // [128][72]
        int vb = blk - 768;
        int bh = vb >> 4, b = bh >> 3, h = bh & 7;
        int c128 = vb & 15;
        int j0 = c128 << 7;
#pragma unroll
        for (int it = 0; it < 4; ++it) {
            int idx = tid + (it << 8);       // 0..1023
            int row = idx >> 3, c8 = (idx & 7) << 3;
            *(bf16x8*)&T[row * 72 + c8] =
                *(const bf16x8*)&qkv[(size_t)(b * L_ + j0 + row) * 1792 + 512 + h * DK_ + c8];
        }
        __syncthreads();
#pragma unroll
        for (int it = 0; it < 4; ++it) {
            int idx = tid + (it << 8);       // 0..1023 = sub*512 + f*64 + l
            int sub = idx >> 9;
            int rem = idx & 511;
            int f = rem >> 6, l = rem & 63;
            int q = l >> 4, tt = l & 15;
            bf16x8 o = *(bf16x8*)&T[(sub * 64 + (f >> 1) * 16 + tt) * 72 + ((f & 1) << 5) + (q << 3)];
            int jt = (c128 << 1) + sub;
            *(bf16x8*)&kT[((((size_t)bh * 32 + jt) * 8 + f) * 64 + l) * 8] = o;
        }
    }
}

// ---------------------------------------------------------------------------
// Flash attention (r11 body): barrier-free main loop, 4-way j-split, TWO
// i-row-groups per wave, staged bias precompute.
// REGISTER-CEILING LEDGER (do not repeat):
//  - r5  (256,8): 64-reg cap  -> 941 MB spill; r6 (256,5): 96-cap -> 420 MB
//  - r8  bias-all16 @(256,4) -> 33 MB spill; r12 kf-next-tile prefetch
//    @(256,3) (32-reg live range across PV) -> 126 MB spill.
//  The r11 body is AT the ceiling; only additions that DIE before the next
//  long-latency section fit. Verified: flash ~52 us, VGPR 84, WRITE 7.8 MB.
// XCD-affine: id&7 = head-pair -> kT/vT L2-resident per XCD.
// ---------------------------------------------------------------------------
__global__ __launch_bounds__(256, 3) void flash_kernel(
    const short* __restrict__ qkv, const short* __restrict__ kT,
    const short* __restrict__ vT, const float* __restrict__ Tg,
    const unsigned char* __restrict__ sidx_g, short* __restrict__ ao)
{
    __shared__ __align__(16) char arena[27136];
    int tid = threadIdx.x;
    int w = tid >> 6, lane = tid & 63, quad = lane >> 4, t = lane & 15;
    short* Pla = (short*)(arena + w * 4608);                // [16][72]
    short* Plb = (short*)(arena + w * 4608 + 2304);         // [16][72]
    float* Tt = (float*)(arena + 18432);                    // [32][36] = 4608
    unsigned char* sidxl = (unsigned char*)(arena + 23040); // 4096 -> 27136

    int id = blockIdx.x;
    int bh8 = id & 7, rest = id >> 3;     // rest 0..127
    int x = rest & 63, hi = rest >> 6;
    int bh = bh8 + (hi << 3);
    int b = bh >> 3, h = bh & 7;
    int i0 = x << 5;                       // 32 i-rows per block

    for (int idx = tid; idx < 32 * 35; idx += 256) {
        int il = idx / 35, s = idx - il * 35;
        Tt[il * 36 + s] = Tg[(size_t)(b * L_ + i0 + il) * 280 + h * 35 + s];
    }
    for (int idx = tid; idx < 4095; idx += 256) sidxl[idx] = sidx_g[idx];
    __syncthreads();

    const short* qa = qkv + (size_t)(b * L_ + i0 + t) * 1792 + h * DK_;
    const short* qb = qkv + (size_t)(b * L_ + i0 + 16 + t) * 1792 + h * DK_;
    bf16x8 qf0a = *(const bf16x8*)(qa + (quad << 3));
    bf16x8 qf1a = *(const bf16x8*)(qa + 32 + (quad << 3));
    bf16x8 qf0b = *(const bf16x8*)(qb + (quad << 3));
    bf16x8 qf1b = *(const bf16x8*)(qb + 32 + (quad << 3));

    f32x4 Oa[6] = {}, Ob[6] = {};
    float lsa[4] = {0.f, 0.f, 0.f, 0.f};
    float lsb[4] = {0.f, 0.f, 0.f, 0.f};
    const short* kfb = kT + (size_t)bh * 32 * 8 * 512 + lane * 8;
    const short* vfb = vT + (size_t)bh * 32 * 12 * 512 + lane * 8;

    for (int tix = 0; tix < 8; ++tix) {
        int jt = (tix << 2) + w;
        int j0 = jt << 6;
        bf16x8 kf[8];
#pragma unroll
        for (int f = 0; f < 8; ++f)
            kf[f] = *(const bf16x8*)(kfb + ((size_t)jt * 8 + f) * 512);

        // bias A gathers: only need (i,j); complete under kf wait + QKa
        float bA[16];
#pragma unroll
        for (int r = 0; r < 4; ++r) {
            int il = (quad << 2) + r;
            int i = i0 + il;
            const float* Trow = &Tt[il * 36];
#pragma unroll
            for (int ct = 0; ct < 4; ++ct)
                bA[r * 4 + ct] = Trow[sidxl[j0 + ct * 16 + t - i + 2047]];
        }
        __builtin_amdgcn_sched_barrier(0);

        f32x4 S[4];
        __builtin_amdgcn_s_setprio(1);
#pragma unroll
        for (int ct = 0; ct < 4; ++ct) {
            f32x4 z = {};
            z = __builtin_amdgcn_mfma_f32_16x16x32_bf16(qf0a, kf[ct * 2], z, 0, 0, 0);
            S[ct] = __builtin_amdgcn_mfma_f32_16x16x32_bf16(qf1a, kf[ct * 2 + 1], z, 0, 0, 0);
        }
        __builtin_amdgcn_s_setprio(0);
        // softmax A: exp-only (bias already in regs); S dies here
#pragma unroll
        for (int r = 0; r < 4; ++r) {
            int il = (quad << 2) + r;
            bf16x4 pv;
#pragma unroll
            for (int ct = 0; ct < 4; ++ct) {
                float p = __expf(S[ct][r] + bA[r * 4 + ct]);
                __bf16 pb = (__bf16)p;
                pv[ct] = pb;
                lsa[r] += (float)pb;
            }
            *(bf16x4*)&Pla[il * 72 + t * 4] = pv;   // position p = t*4+ct
        }
        // bias B gathers: complete under QKb + vf issue (bA dead above)
        float bB[16];
#pragma unroll
        for (int r = 0; r < 4; ++r) {
            int il = (quad << 2) + r;
            int i = i0 + 16 + il;
            const float* Trow = &Tt[(16 + il) * 36];
#pragma unroll
            for (int ct = 0; ct < 4; ++ct)
                bB[r * 4 + ct] = Trow[sidxl[j0 + ct * 16 + t - i + 2047]];
        }
        __builtin_amdgcn_s_setprio(1);
#pragma unroll
        for (int ct = 0; ct < 4; ++ct) {
            f32x4 z = {};
            z = __builtin_amdgcn_mfma_f32_16x16x32_bf16(qf0b, kf[ct * 2], z, 0, 0, 0);
            S[ct] = __builtin_amdgcn_mfma_f32_16x16x32_bf16(qf1b, kf[ct * 2 + 1], z, 0, 0, 0);
        }
        __builtin_amdgcn_s_setprio(0);

        bf16x8 vf[12];
#pragma unroll
        for (int f = 0; f < 12; ++f)
            vf[f] = *(const bf16x8*)(vfb + ((size_t)jt * 12 + f) * 512);
        __builtin_amdgcn_sched_barrier(0);
        // softmax B: exp-only (covers vf latency)
#pragma unroll
        for (int r = 0; r < 4; ++r) {
            int il = (quad << 2) + r;
            bf16x4 pv;
#pragma unroll
            for (int ct = 0; ct < 4; ++ct) {
                float p = __expf(S[ct][r] + bB[r * 4 + ct]);
                __bf16 pb = (__bf16)p;
                pv[ct] = pb;
                lsb[r] += (float)pb;
            }
            *(bf16x4*)&Plb[il * 72 + t * 4] = pv;
        }
        __builtin_amdgcn_s_setprio(1);
#pragma unroll
        for (int ks = 0; ks < 2; ++ks) {
            bf16x8 paa = *(bf16x8*)&Pla[t * 72 + (ks << 5) + (quad << 3)];
            bf16x8 pab = *(bf16x8*)&Plb[t * 72 + (ks << 5) + (quad << 3)];
#pragma unroll
            for (int dv = 0; dv < 6; ++dv) {
                Oa[dv] = __builtin_amdgcn_mfma_f32_16x16x32_bf16(paa, vf[dv * 2 + ks], Oa[dv], 0, 0, 0);
                Ob[dv] = __builtin_amdgcn_mfma_f32_16x16x32_bf16(pab, vf[dv * 2 + ks], Ob[dv], 0, 0, 0);
            }
        }
        __builtin_amdgcn_s_setprio(0);
    }

    // tree-combine 4 partials per row-group (sequential F reuse; arena dead)
    float* F = (float*)arena;     // [28][128] floats = 14336 B
#pragma unroll
    for (int g = 0; g < 2; ++g) {
        f32x4* O = g ? Ob : Oa;
        float* ls = g ? lsb : lsa;
        __syncthreads();
        if (w >= 2) {
            int col = ((w - 2) << 6) + lane;
#pragma unroll
            for (int dv = 0; dv < 6; ++dv)
#pragma unroll
                for (int r = 0; r < 4; ++r)
                    F[((dv << 2) + r) * 128 + col] = O[dv][r];
#pragma unroll
            for (int r = 0; r < 4; ++r) F[(24 + r) * 128 + col] = ls[r];
        }
        __syncthreads();
        if (w < 2) {
            int col = (w << 6) + lane;
#pragma unroll
            for (int dv = 0; dv < 6; ++dv)
#pragma unroll
                for (int r = 0; r < 4; ++r)
                    O[dv][r] += F[((dv << 2) + r) * 128 + col];
#pragma unroll
            for (int r = 0; r < 4; ++r) ls[r] += F[(24 + r) * 128 + col];
        }
        __syncthreads();
        if (w == 1) {
            int col = 64 + lane;
#pragma unroll
            for (int dv = 0; dv < 6; ++dv)
#pragma unroll
                for (int r = 0; r < 4; ++r)
                    F[((dv << 2) + r) * 128 + col] = O[dv][r];
#pragma unroll
            for (int r = 0; r < 4; ++r) F[(24 + r) * 128 + col] = ls[r];
        }
        __syncthreads();
        if (w == 0) {
            int col = 64 + lane;
#pragma unroll
            for (int r = 0; r < 4; ++r) {
                float lr = ls[r] + F[(24 + r) * 128 + col];
                lr += __shfl_xor(lr, 1);
                lr += __shfl_xor(lr, 2);
                lr += __shfl_xor(lr, 4);
                lr += __shfl_xor(lr, 8);
                float inv = 1.f / lr;
                int i = i0 + (g << 4) + (quad << 2) + r;
                size_t base = (size_t)(b * L_ + i) * D_ + h * DV_;
#pragma unroll
                for (int dv = 0; dv < 6; ++dv)
                    ao[base + dv * 16 + t] = f2bs((O[dv][r] + F[((dv << 2) + r) * 128 + col]) * inv);
            }
        }
    }
}

// ---------------------------------------------------------------------------
extern "C" void kernel_launch(void* const* d_in, const int* in_sizes, int n_in,
                              void* d_out, int out_size, void* d_ws, size_t ws_size,
                              hipStream_t stream)
{
    const float* x    = (const float*)d_in[0];
    const float* n1w  = (const float*)d_in[1];
    const float* n2w  = (const float*)d_in[2];
    const float* wq   = (const float*)d_in[3];
    const float* wk   = (const float*)d_in[4];
    const float* wv   = (const float*)d_in[5];
    const float* wo   = (const float*)d_in[6];
    const float* bo   = (const float*)d_in[7];
    const float* up   = (const float*)d_in[8];
    const float* vp   = (const float*)d_in[9];
    const float* wpos = (const float*)d_in[10];
    const float* w1   = (const float*)d_in[11];
    const float* b1   = (const float*)d_in[12];
    const float* w2   = (const float*)d_in[13];
    const float* b2   = (const float*)d_in[14];

    char* ws = (char*)d_ws;
    short* h1   = (short*)(ws + 0);         // [4096,768] bf16
    short* qkv  = (short*)(ws + 6291456);   // [4096,1792] bf16, ends 20971520
    float* Tg   = (float*)(ws + 20971520);  // [4096,8,35] f32, ends 25559040
    float* VUg  = (float*)(ws + 25559040);
    float* VSg  = (float*)(ws + 25560064);
    unsigned char* sidx = (unsigned char*)(ws + 25561088);  // [4096]
    short* ao   = (short*)(ws + 25569280);  // [4096,768] bf16
    float* x2   = (float*)(ws + 31860736);  // [4096,768] f32, ends 44443648
    short* vT   = (short*)(ws + 31860736);  // [16,32,12,64,8] bf16 overlays x2 (dead before wo-gemm)
    short* kT   = (short*)(ws + 38152192);  // [16,32,8,64,8] bf16, also in x2 overlay, ends 42346496
    short* wqkvT= (short*)(ws + 44443648);  // [1792,768] bf16, ends 47196160
    short* woT  = (short*)(ws + 47196160);  // [768,768]
    short* w1T  = (short*)(ws + 48375808);  // [1536,768]
    short* w2T  = (short*)(ws + 50735104);  // [768,1536], ends 53094400
    short* f1   = (short*)(ws + 0);         // [4096,1536] overlays h1+qkv head (dead)
    short* h2n  = (short*)(ws + 14680064);  // [4096,768] overlays qkv tail (dead)

    prep_kernel<<<5153, 256, 0, stream>>>(wq, wk, wv, wo, w1, w2, vp, up, wpos,
                                          wqkvT, woT, w1T, w2T, sidx, VUg, VSg,
                                          x, n1w, h1);
    gemmx<128><<<dim3(14, 32), 512, 0, stream>>>(h1, wqkvT, nullptr, up, nullptr, qkv, 4096, 1792, 768, 0, 0);
    qv_kernel<<<1024, 256, 0, stream>>>(qkv, wpos, VUg, VSg, Tg, vT, kT);
    flash_kernel<<<dim3(1024), 256, 0, stream>>>(qkv, kT, vT, Tg, sidx, ao);
    gemmx<64><<<dim3(12, 32), 512, 0, stream>>>(ao, woT, bo, nullptr, x, x2, 4096, 768, 768, 0, 1);
    rmsnorm_kernel<<<4096, 256, 0, stream>>>(x2, n2w, h2n);
    gemmx<128><<<dim3(12, 32), 512, 0, stream>>>(h2n, w1T, b1, nullptr, nullptr, f1, 4096, 1536, 768, 1, 0);
    gemmx<64><<<dim3(12, 32), 512, 0, stream>>>(f1, w2T, b2, nullptr, x2, d_out, 4096, 768, 1536, 0, 1);
}

// Round 15
// 260.290 us; speedup vs baseline: 1.0647x; 1.0647x over previous
//
#include <hip/hip_runtime.h>

#define B_ 2
#define L_ 2048
#define D_ 768
#define H_ 8
#define DK_ 64
#define DV_ 96
#define NPOS_ 32

typedef __attribute__((ext_vector_type(8))) __bf16 bf16x8;
typedef __attribute__((ext_vector_type(4))) __bf16 bf16x4;
typedef __attribute__((ext_vector_type(4))) float f32x4;

static __device__ __forceinline__ float bs2f(short s) {
    return (float)__builtin_bit_cast(__bf16, s);
}
static __device__ __forceinline__ short f2bs(float f) {
    return __builtin_bit_cast(short, (__bf16)f);
}

typedef __attribute__((address_space(1))) void gas_void;
typedef __attribute__((address_space(3))) void las_void;
static __device__ __forceinline__ void gload16(const short* g, char* l) {
    __builtin_amdgcn_global_load_lds((const gas_void*)g, (las_void*)l, 16, 0, 0);
}

// ---------------------------------------------------------------------------
// prep (fused with rmsnorm1): blocks 0..1055 transpose weights; block 1056
// builds sidx + VU/VS tables; blocks 1057.. do rmsnorm rows of x -> h1.
// sidx: cw table computed ONCE into shared (r8: was 256 powf/thread).
// ---------------------------------------------------------------------------
__global__ __launch_bounds__(256) void prep_kernel(
    const float* __restrict__ wq, const float* __restrict__ wk,
    const float* __restrict__ wv, const float* __restrict__ wo,
    const float* __restrict__ w1, const float* __restrict__ w2,
    const float* __restrict__ vparam, const float* __restrict__ uparam,
    const float* __restrict__ wpos,
    short* __restrict__ wqkvT, short* __restrict__ woT,
    short* __restrict__ w1T, short* __restrict__ w2T,
    unsigned char* __restrict__ sidx, float* __restrict__ VU, float* __restrict__ VS,
    const float* __restrict__ x, const float* __restrict__ n1w, short* __restrict__ h1)
{
    __shared__ short T[64][66];
    __shared__ float vw[H_ * NPOS_];
    __shared__ float uw[H_ * NPOS_];
    __shared__ float red[4];
    int blk = blockIdx.x, tid = threadIdx.x;
    if (blk < 1056) {
        const float* W; short* Wt; int K, N, bx, by;
        if (blk < 96)       { W = wq; Wt = wqkvT;              K = 768;  N = 512;  int b = blk;       bx = b % 8;  by = b / 8; }
        else if (blk < 192) { W = wk; Wt = wqkvT + 512 * 768;  K = 768;  N = 512;  int b = blk - 96;  bx = b % 8;  by = b / 8; }
        else if (blk < 336) { W = wv; Wt = wqkvT + 1024 * 768; K = 768;  N = 768;  int b = blk - 192; bx = b % 12; by = b / 12; }
        else if (blk < 480) { W = wo; Wt = woT;                K = 768;  N = 768;  int b = blk - 336; bx = b % 12; by = b / 12; }
        else if (blk < 768) { W = w1; Wt = w1T;                K = 768;  N = 1536; int b = blk - 480; bx = b % 24; by = b / 24; }
        else                { W = w2; Wt = w2T;                K = 1536; N = 768;  int b = blk - 768; bx = b % 12; by = b / 12; }
        int n0 = bx << 6, k0 = by << 6;
        for (int idx = tid; idx < 4096; idx += 256) {
            int r = idx >> 6, c = idx & 63;
            T[c][r] = f2bs(W[(size_t)(k0 + r) * N + n0 + c]);
        }
        __syncthreads();
        for (int idx = tid; idx < 4096; idx += 256) {
            int r = idx >> 6, c = idx & 63;
            Wt[(size_t)(n0 + r) * K + k0 + c] = T[r][c];
        }
    } else if (blk == 1056) {
        float pr = expf(logf((L_ + 1) / 2.0f) / (NPOS_ / 2));
        if (tid < 16) vw[tid] = powf(pr, (float)(tid + 1));   // cw table, once
        __syncthreads();
        for (int idx = tid; idx < 4095; idx += 256) {
            int d = idx - 2047;
            int ad = d < 0 ? -d : d;
            int c = 0;
#pragma unroll
            for (int m = 0; m < 16; ++m)
                if (vw[m] < (float)ad) c++;
            sidx[idx] = (unsigned char)(d > 0 ? c : (d < 0 ? 17 + c : 34));
        }
        __syncthreads();
        {
            int h = tid >> 5, n = tid & 31;
            float av = 0.f, au = 0.f;
            for (int d = 0; d < DK_; ++d) {
                float wp = wpos[(h * DK_ + d) * NPOS_ + n];
                av += vparam[h * DK_ + d] * wp;
                au += uparam[h * DK_ + d] * wp;
            }
            vw[tid] = av;
            uw[tid] = au;
        }
        __syncthreads();
        if (tid < H_ * 17) {
            int h = tid / 17, m = tid % 17;
            float su = 0.f, ss = 0.f;
            for (int t2 = m; t2 < 16; ++t2) {
                su += vw[h * NPOS_ + t2] - uw[h * NPOS_ + t2];
                ss += vw[h * NPOS_ + 16 + t2] - uw[h * NPOS_ + 16 + t2];
            }
            VU[h * 17 + m] = su * 0.125f;
            VS[h * 17 + m] = ss * 0.125f;
        }
    } else {
        int row = blk - 1057;
        const float* xr = x + (size_t)row * D_;
        float ss = 0.f;
        for (int c = tid; c < D_; c += 256) { float f = xr[c]; ss += f * f; }
        for (int msk = 1; msk < 64; msk <<= 1) ss += __shfl_xor(ss, msk);
        if ((tid & 63) == 0) red[tid >> 6] = ss;
        __syncthreads();
        float tot = red[0] + red[1] + red[2] + red[3];
        float sc = rsqrtf(tot * (1.f / D_) + 1e-5f);
        for (int c = tid; c < D_; c += 256)
            h1[(size_t)row * D_ + c] = f2bs(xr[c] * sc * n1w[c]);
    }
}

// ---------------------------------------------------------------------------
// RMSNorm (row of 768), fp32 in, bf16 out (second norm only)
// ---------------------------------------------------------------------------
__global__ __launch_bounds__(256) void rmsnorm_kernel(
    const float* __restrict__ x, const float* __restrict__ wgt, short* __restrict__ out)
{
    int row = blockIdx.x, tid = threadIdx.x;
    __shared__ float red[4];
    const float* xr = x + (size_t)row * D_;
    float ss = 0.f;
    for (int c = tid; c < D_; c += 256) { float f = xr[c]; ss += f * f; }
    for (int msk = 1; msk < 64; msk <<= 1) ss += __shfl_xor(ss, msk);
    if ((tid & 63) == 0) red[tid >> 6] = ss;
    __syncthreads();
    float tot = red[0] + red[1] + red[2] + red[3];
    float sc = rsqrtf(tot * (1.f / D_) + 1e-5f);
    for (int c = tid; c < D_; c += 256)
        out[(size_t)row * D_ + c] = f2bs(xr[c] * sc * wgt[c]);
}

// ---------------------------------------------------------------------------
// gemmx (r13 2-phase, VERBATIM REVERT from r14): BK=64 double-buffered
// global_load_lds staging, both-sides XOR swizzle, 512 threads / 8 waves.
// GEMM-STRUCTURE LEDGER (do not repeat):
//  - r14 BK=32 triple-buffer + counted vmcnt(2): halved MFMA:ds_read ratio
//    (2.67 -> 1.33 per b128) and MFMA-per-barrier (32 -> 8) -> +15 us total.
//    T4 counted-vmcnt requires preserving the MFMA:LDS ratio (8-phase-style
//    sub-phases), which at these tile sizes costs LDS/occupancy instead.
// This 2-phase BK=64 form is the best verified structure at M=4096, N<=1792.
// ---------------------------------------------------------------------------
template<int BN>
__global__ __launch_bounds__(512, 4) void gemmx(
    const short* __restrict__ A, const short* __restrict__ Bt,
    const float* __restrict__ bias, const float* __restrict__ uadd,
    const float* __restrict__ resid, void* __restrict__ outp,
    int M, int N, int K, int act, int out_f32)
{
    constexpr int STRIDE = 16384 + BN * 128;       // bytes per buffer
    __shared__ __align__(16) char ldsb[2 * STRIDE];
    int tid = threadIdx.x;
    int w = tid >> 6, lane = tid & 63, quad = lane >> 4, t = lane & 15;
    int wm = (w >> 1) << 5;                        // 4 wave-rows of 32
    int wn = (w & 1) * (BN / 2);                   // 2 wave-cols
    int m0b = blockIdx.y << 7, n0b = blockIdx.x * BN;

    // staging: thread covers row srow(+64), 8 shorts at swizzled col
    int srow = tid >> 3;
    int scol = ((tid & 7) ^ (srow & 7)) << 3;
    const short* aSrc0 = A + (size_t)(m0b + srow) * K + scol;
    const short* aSrc1 = A + (size_t)(m0b + 64 + srow) * K + scol;
    const short* bSrc0 = Bt + (size_t)(n0b + srow) * K + scol;
    const short* bSrc1 = Bt + (size_t)(n0b + 64 + srow) * K + scol;  // BN=128 only
    int wo1024 = w << 10;

    f32x4 acc[2][BN / 32] = {};

    // prologue: stage kb=0 into buf0
    gload16(aSrc0, ldsb + wo1024);
    gload16(aSrc1, ldsb + 8192 + wo1024);
    gload16(bSrc0, ldsb + 16384 + wo1024);
    if (BN == 128) gload16(bSrc1, ldsb + 16384 + 8192 + wo1024);

    int swz = (t & 7) << 4;
    int cur = 0;
    for (int kb = 0; kb < K; kb += 64) {
        __syncthreads();                           // buf[cur] ready
        if (kb + 64 < K) {
            char* nb = ldsb + (cur ^ 1) * STRIDE;
            gload16(aSrc0 + kb + 64, nb + wo1024);
            gload16(aSrc1 + kb + 64, nb + 8192 + wo1024);
            gload16(bSrc0 + kb + 64, nb + 16384 + wo1024);
            if (BN == 128) gload16(bSrc1 + kb + 64, nb + 16384 + 8192 + wo1024);
        }
        char* Ab = ldsb + cur * STRIDE;
        char* Bb = Ab + 16384;
#pragma unroll
        for (int ks = 0; ks < 2; ++ks) {
            int cb = ((ks << 6) + (quad << 4)) ^ swz;
            bf16x8 af[2], bf[BN / 32];
#pragma unroll
            for (int ms = 0; ms < 2; ++ms)
                af[ms] = *(const bf16x8*)(Ab + (wm + ms * 16 + t) * 128 + cb);
#pragma unroll
            for (int ns = 0; ns < BN / 32; ++ns)
                bf[ns] = *(const bf16x8*)(Bb + (wn + ns * 16 + t) * 128 + cb);
#pragma unroll
            for (int ms = 0; ms < 2; ++ms)
#pragma unroll
                for (int ns = 0; ns < BN / 32; ++ns)
                    acc[ms][ns] = __builtin_amdgcn_mfma_f32_16x16x32_bf16(af[ms], bf[ns], acc[ms][ns], 0, 0, 0);
        }
        cur ^= 1;
    }
#pragma unroll
    for (int ms = 0; ms < 2; ++ms)
#pragma unroll
        for (int ns = 0; ns < BN / 32; ++ns)
#pragma unroll
            for (int r = 0; r < 4; ++r) {
                int row = m0b + wm + ms * 16 + (quad << 2) + r;
                int col = n0b + wn + ns * 16 + t;
                float v2 = acc[ms][ns][r];
                if (uadd && col < 512) v2 = 0.125f * (v2 + uadd[col]);
                if (bias) v2 += bias[col];
                if (act == 1) v2 = 0.5f * v2 * (1.f + erff(v2 * 0.70710678118654752f));
                if (resid) v2 += resid[(size_t)row * N + col];
                if (out_f32) ((float*)outp)[(size_t)row * N + col] = v2;
                else ((short*)outp)[(size_t)row * N + col] = f2bs(v2);
            }
}

// ---------------------------------------------------------------------------
// qv: fused qsuf (blocks 0..511, 8 rows each) + fragment-linear vtrans
// (512..767) + fragment-linear ktrans (768..1023).
// qsuf: wpos slice lives in 64 VGPRs (thread-invariant); q read per-row
// straight from global as bf16x8; LDS only for qw/sU/sS reductions.
// vT: [bh][jt=32][f=dv*2+ks][lane=64][8]; frag[l=(q,t)][e] =
//     V[j0 + (e&3)*16 + ks*8 + q*2 + (e>>2)][dv*16+t].
// kT: [bh][jt=32][f=ct*2+half][lane=64][8]; frag[l=(q,t)][e] =
//     K[j0 + ct*16 + t][half*32 + q*8 + e]  (contiguous 16B per lane).
// ---------------------------------------------------------------------------
__global__ __launch_bounds__(256) void qv_kernel(
    const short* __restrict__ qkv, const float* __restrict__ wpos,
    const float* __restrict__ VU, const float* __restrict__ VS,
    float* __restrict__ Tg, short* __restrict__ vT, short* __restrict__ kT)
{
    __shared__ __align__(16) char arena[69696];
    int blk = blockIdx.x, tid = threadIdx.x;
    if (blk < 512) {
        float* qw = (float*)arena;              // 256
        float* sU = (float*)(arena + 1024);     // 136
        float* sS = (float*)(arena + 1568);     // 136
        int h = tid >> 5, n = tid & 31;
        float wlr[64];
#pragma unroll
        for (int d = 0; d < DK_; ++d)
            wlr[d] = wpos[(h * DK_ + d) * NPOS_ + n];
        int r0 = blk << 3;
        for (int rr = 0; rr < 8; ++rr) {
            int row = r0 + rr;
            const short* base = qkv + (size_t)row * 1792 + h * DK_;
            float acc = 0.f;
#pragma unroll
            for (int c8 = 0; c8 < 8; ++c8) {
                bf16x8 q8 = *(const bf16x8*)(base + (c8 << 3));
#pragma unroll
                for (int e = 0; e < 8; ++e)
                    acc += (float)q8[e] * wlr[(c8 << 3) + e];
            }
            qw[tid] = acc;
            __syncthreads();
            if (tid < 136) {
                int hh = tid / 17, m = tid % 17;
                float su = 0.f, ss = 0.f;
                for (int t2 = m; t2 < 16; ++t2) { su += qw[hh * NPOS_ + t2]; ss += qw[hh * NPOS_ + 16 + t2]; }
                sU[tid] = su + VU[tid];
                sS[tid] = ss + VS[tid];
            }
            __syncthreads();
            if (tid < 280) {
                int h2 = tid / 35, s = tid % 35;
                int m = s < 17 ? s : (s < 34 ? s - 17 : 0);
                float su = sU[h2 * 17 + m], ss = sS[h2 * 17 + m];
                Tg[(size_t)row * 280 + tid] = s < 17 ? su + ss : (s < 34 ? su - ss : su);
            }
        }
    } else if (blk < 768) {
        short* T = (short*)arena;   // [128][104]
        int vb = blk - 512;
        int bh = vb >> 4, b = bh >> 3, h = bh & 7;
        int j0 = (vb & 15) << 7;
#pragma unroll
        for (int it = 0; it < 6; ++it) {
            int idx = tid + (it << 8);
            int row = idx / 12, c8 = (idx % 12) << 3;
            *(bf16x8*)&T[row * 104 + c8] =
                *(const bf16x8*)&qkv[(size_t)(b * L_ + j0 + row) * 1792 + 1024 + h * DV_ + c8];
        }
        __syncthreads();
#pragma unroll
        for (int it = 0; it < 6; ++it) {
            int idx = tid + (it << 8);       // 0..1535 = sub*768 + f*64 + l
            int sub = idx / 768;
            int rem = idx - sub * 768;
            int f = rem >> 6, l = rem & 63;
            int dv = f >> 1, ks = f & 1;
            int q = l >> 4, t = l & 15;
            bf16x8 o;
#pragma unroll
            for (int e = 0; e < 8; ++e) {
                int jl = ((e & 3) << 4) + (ks << 3) + (q << 1) + (e >> 2);
                o[e] = __builtin_bit_cast(__bf16, T[(sub * 64 + jl) * 104 + dv * 16 + t]);
            }
            int jt = ((vb & 15) << 1) + sub;
            *(bf16x8*)&vT[((((size_t)bh * 32 + jt) * 12 + f) * 64 + l) * 8] = o;
        }
    } else {
        short* T = (short*)arena;   // [128][72]
        int vb = blk - 768;
        int bh = vb >> 4, b = bh >> 3, h = bh & 7;
        int c128 = vb & 15;
        int j0 = c128 << 7;
#pragma unroll
        for (int it = 0; it < 4; ++it) {
            int idx = tid + (it << 8);       // 0..1023
            int row = idx >> 3, c8 = (idx & 7) << 3;
            *(bf16x8*)&T[row * 72 + c8] =
                *(const bf16x8*)&qkv[(size_t)(b * L_ + j0 + row) * 1792 + 512 + h * DK_ + c8];
        }
        __syncthreads();
#pragma unroll
        for (int it = 0; it < 4; ++it) {
            int idx = tid + (it << 8);       // 0..1023 = sub*512 + f*64 + l
            int sub = idx >> 9;
            int rem = idx & 511;
            int f = rem >> 6, l = rem & 63;
            int q = l >> 4, tt = l & 15;
            bf16x8 o = *(bf16x8*)&T[(sub * 64 + (f >> 1) * 16 + tt) * 72 + ((f & 1) << 5) + (q << 3)];
            int jt = (c128 << 1) + sub;
            *(bf16x8*)&kT[((((size_t)bh * 32 + jt) * 8 + f) * 64 + l) * 8] = o;
        }
    }
}

// ---------------------------------------------------------------------------
// Flash attention (r11 body): barrier-free main loop, 4-way j-split, TWO
// i-row-groups per wave, staged bias precompute.
// REGISTER-CEILING LEDGER (do not repeat):
//  - r5  (256,8): 64-reg cap  -> 941 MB spill; r6 (256,5): 96-cap -> 420 MB
//  - r8  bias-all16 @(256,4) -> 33 MB spill; r12 kf-next-tile prefetch
//    @(256,3) (32-reg live range across PV) -> 126 MB spill.
//  The r11 body is AT the ceiling; only additions that DIE before the next
//  long-latency section fit. Verified: flash ~47-52 us, VGPR 84, WRITE 7.8 MB.
// XCD-affine: id&7 = head-pair -> kT/vT L2-resident per XCD.
// ---------------------------------------------------------------------------
__global__ __launch_bounds__(256, 3) void flash_kernel(
    const short* __restrict__ qkv, const short* __restrict__ kT,
    const short* __restrict__ vT, const float* __restrict__ Tg,
    const unsigned char* __restrict__ sidx_g, short* __restrict__ ao)
{
    __shared__ __align__(16) char arena[27136];
    int tid = threadIdx.x;
    int w = tid >> 6, lane = tid & 63, quad = lane >> 4, t = lane & 15;
    short* Pla = (short*)(arena + w * 4608);                // [16][72]
    short* Plb = (short*)(arena + w * 4608 + 2304);         // [16][72]
    float* Tt = (float*)(arena + 18432);                    // [32][36] = 4608
    unsigned char* sidxl = (unsigned char*)(arena + 23040); // 4096 -> 27136

    int id = blockIdx.x;
    int bh8 = id & 7, rest = id >> 3;     // rest 0..127
    int x = rest & 63, hi = rest >> 6;
    int bh = bh8 + (hi << 3);
    int b = bh >> 3, h = bh & 7;
    int i0 = x << 5;                       // 32 i-rows per block

    for (int idx = tid; idx < 32 * 35; idx += 256) {
        int il = idx / 35, s = idx - il * 35;
        Tt[il * 36 + s] = Tg[(size_t)(b * L_ + i0 + il) * 280 + h * 35 + s];
    }
    for (int idx = tid; idx < 4095; idx += 256) sidxl[idx] = sidx_g[idx];
    __syncthreads();

    const short* qa = qkv + (size_t)(b * L_ + i0 + t) * 1792 + h * DK_;
    const short* qb = qkv + (size_t)(b * L_ + i0 + 16 + t) * 1792 + h * DK_;
    bf16x8 qf0a = *(const bf16x8*)(qa + (quad << 3));
    bf16x8 qf1a = *(const bf16x8*)(qa + 32 + (quad << 3));
    bf16x8 qf0b = *(const bf16x8*)(qb + (quad << 3));
    bf16x8 qf1b = *(const bf16x8*)(qb + 32 + (quad << 3));

    f32x4 Oa[6] = {}, Ob[6] = {};
    float lsa[4] = {0.f, 0.f, 0.f, 0.f};
    float lsb[4] = {0.f, 0.f, 0.f, 0.f};
    const short* kfb = kT + (size_t)bh * 32 * 8 * 512 + lane * 8;
    const short* vfb = vT + (size_t)bh * 32 * 12 * 512 + lane * 8;

    for (int tix = 0; tix < 8; ++tix) {
        int jt = (tix << 2) + w;
        int j0 = jt << 6;
        bf16x8 kf[8];
#pragma unroll
        for (int f = 0; f < 8; ++f)
            kf[f] = *(const bf16x8*)(kfb + ((size_t)jt * 8 + f) * 512);

        // bias A gathers: only need (i,j); complete under kf wait + QKa
        float bA[16];
#pragma unroll
        for (int r = 0; r < 4; ++r) {
            int il = (quad << 2) + r;
            int i = i0 + il;
            const float* Trow = &Tt[il * 36];
#pragma unroll
            for (int ct = 0; ct < 4; ++ct)
                bA[r * 4 + ct] = Trow[sidxl[j0 + ct * 16 + t - i + 2047]];
        }
        __builtin_amdgcn_sched_barrier(0);

        f32x4 S[4];
        __builtin_amdgcn_s_setprio(1);
#pragma unroll
        for (int ct = 0; ct < 4; ++ct) {
            f32x4 z = {};
            z = __builtin_amdgcn_mfma_f32_16x16x32_bf16(qf0a, kf[ct * 2], z, 0, 0, 0);
            S[ct] = __builtin_amdgcn_mfma_f32_16x16x32_bf16(qf1a, kf[ct * 2 + 1], z, 0, 0, 0);
        }
        __builtin_amdgcn_s_setprio(0);
        // softmax A: exp-only (bias already in regs); S dies here
#pragma unroll
        for (int r = 0; r < 4; ++r) {
            int il = (quad << 2) + r;
            bf16x4 pv;
#pragma unroll
            for (int ct = 0; ct < 4; ++ct) {
                float p = __expf(S[ct][r] + bA[r * 4 + ct]);
                __bf16 pb = (__bf16)p;
                pv[ct] = pb;
                lsa[r] += (float)pb;
            }
            *(bf16x4*)&Pla[il * 72 + t * 4] = pv;   // position p = t*4+ct
        }
        // bias B gathers: complete under QKb + vf issue (bA dead above)
        float bB[16];
#pragma unroll
        for (int r = 0; r < 4; ++r) {
            int il = (quad << 2) + r;
            int i = i0 + 16 + il;
            const float* Trow = &Tt[(16 + il) * 36];
#pragma unroll
            for (int ct = 0; ct < 4; ++ct)
                bB[r * 4 + ct] = Trow[sidxl[j0 + ct * 16 + t - i + 2047]];
        }
        __builtin_amdgcn_s_setprio(1);
#pragma unroll
        for (int ct = 0; ct < 4; ++ct) {
            f32x4 z = {};
            z = __builtin_amdgcn_mfma_f32_16x16x32_bf16(qf0b, kf[ct * 2], z, 0, 0, 0);
            S[ct] = __builtin_amdgcn_mfma_f32_16x16x32_bf16(qf1b, kf[ct * 2 + 1], z, 0, 0, 0);
        }
        __builtin_amdgcn_s_setprio(0);

        bf16x8 vf[12];
#pragma unroll
        for (int f = 0; f < 12; ++f)
            vf[f] = *(const bf16x8*)(vfb + ((size_t)jt * 12 + f) * 512);
        __builtin_amdgcn_sched_barrier(0);
        // softmax B: exp-only (covers vf latency)
#pragma unroll
        for (int r = 0; r < 4; ++r) {
            int il = (quad << 2) + r;
            bf16x4 pv;
#pragma unroll
            for (int ct = 0; ct < 4; ++ct) {
                float p = __expf(S[ct][r] + bB[r * 4 + ct]);
                __bf16 pb = (__bf16)p;
                pv[ct] = pb;
                lsb[r] += (float)pb;
            }
            *(bf16x4*)&Plb[il * 72 + t * 4] = pv;
        }
        __builtin_amdgcn_s_setprio(1);
#pragma unroll
        for (int ks = 0; ks < 2; ++ks) {
            bf16x8 paa = *(bf16x8*)&Pla[t * 72 + (ks << 5) + (quad << 3)];
            bf16x8 pab = *(bf16x8*)&Plb[t * 72 + (ks << 5) + (quad << 3)];
#pragma unroll
            for (int dv = 0; dv < 6; ++dv) {
                Oa[dv] = __builtin_amdgcn_mfma_f32_16x16x32_bf16(paa, vf[dv * 2 + ks], Oa[dv], 0, 0, 0);
                Ob[dv] = __builtin_amdgcn_mfma_f32_16x16x32_bf16(pab, vf[dv * 2 + ks], Ob[dv], 0, 0, 0);
            }
        }
        __builtin_amdgcn_s_setprio(0);
    }

    // tree-combine 4 partials per row-group (sequential F reuse; arena dead)
    float* F = (float*)arena;     // [28][128] floats = 14336 B
#pragma unroll
    for (int g = 0; g < 2; ++g) {
        f32x4* O = g ? Ob : Oa;
        float* ls = g ? lsb : lsa;
        __syncthreads();
        if (w >= 2) {
            int col = ((w - 2) << 6) + lane;
#pragma unroll
            for (int dv = 0; dv < 6; ++dv)
#pragma unroll
                for (int r = 0; r < 4; ++r)
                    F[((dv << 2) + r) * 128 + col] = O[dv][r];
#pragma unroll
            for (int r = 0; r < 4; ++r) F[(24 + r) * 128 + col] = ls[r];
        }
        __syncthreads();
        if (w < 2) {
            int col = (w << 6) + lane;
#pragma unroll
            for (int dv = 0; dv < 6; ++dv)
#pragma unroll
                for (int r = 0; r < 4; ++r)
                    O[dv][r] += F[((dv << 2) + r) * 128 + col];
#pragma unroll
            for (int r = 0; r < 4; ++r) ls[r] += F[(24 + r) * 128 + col];
        }
        __syncthreads();
        if (w == 1) {
            int col = 64 + lane;
#pragma unroll
            for (int dv = 0; dv < 6; ++dv)
#pragma unroll
                for (int r = 0; r < 4; ++r)
                    F[((dv << 2) + r) * 128 + col] = O[dv][r];
#pragma unroll
            for (int r = 0; r < 4; ++r) F[(24 + r) * 128 + col] = ls[r];
        }
        __syncthreads();
        if (w == 0) {
            int col = 64 + lane;
#pragma unroll
            for (int r = 0; r < 4; ++r) {
                float lr = ls[r] + F[(24 + r) * 128 + col];
                lr += __shfl_xor(lr, 1);
                lr += __shfl_xor(lr, 2);
                lr += __shfl_xor(lr, 4);
                lr += __shfl_xor(lr, 8);
                float inv = 1.f / lr;
                int i = i0 + (g << 4) + (quad << 2) + r;
                size_t base = (size_t)(b * L_ + i) * D_ + h * DV_;
#pragma unroll
                for (int dv = 0; dv < 6; ++dv)
                    ao[base + dv * 16 + t] = f2bs((O[dv][r] + F[((dv << 2) + r) * 128 + col]) * inv);
            }
        }
    }
}

// ---------------------------------------------------------------------------
extern "C" void kernel_launch(void* const* d_in, const int* in_sizes, int n_in,
                              void* d_out, int out_size, void* d_ws, size_t ws_size,
                              hipStream_t stream)
{
    const float* x    = (const float*)d_in[0];
    const float* n1w  = (const float*)d_in[1];
    const float* n2w  = (const float*)d_in[2];
    const float* wq   = (const float*)d_in[3];
    const float* wk   = (const float*)d_in[4];
    const float* wv   = (const float*)d_in[5];
    const float* wo   = (const float*)d_in[6];
    const float* bo   = (const float*)d_in[7];
    const float* up   = (const float*)d_in[8];
    const float* vp   = (const float*)d_in[9];
    const float* wpos = (const float*)d_in[10];
    const float* w1   = (const float*)d_in[11];
    const float* b1   = (const float*)d_in[12];
    const float* w2   = (const float*)d_in[13];
    const float* b2   = (const float*)d_in[14];

    char* ws = (char*)d_ws;
    short* h1   = (short*)(ws + 0);         // [4096,768] bf16
    short* qkv  = (short*)(ws + 6291456);   // [4096,1792] bf16, ends 20971520
    float* Tg   = (float*)(ws + 20971520);  // [4096,8,35] f32, ends 25559040
    float* VUg  = (float*)(ws + 25559040);
    float* VSg  = (float*)(ws + 25560064);
    unsigned char* sidx = (unsigned char*)(ws + 25561088);  // [4096]
    short* ao   = (short*)(ws + 25569280);  // [4096,768] bf16
    float* x2   = (float*)(ws + 31860736);  // [4096,768] f32, ends 44443648
    short* vT   = (short*)(ws + 31860736);  // [16,32,12,64,8] bf16 overlays x2 (dead before wo-gemm)
    short* kT   = (short*)(ws + 38152192);  // [16,32,8,64,8] bf16, also in x2 overlay, ends 42346496
    short* wqkvT= (short*)(ws + 44443648);  // [1792,768] bf16, ends 47196160
    short* woT  = (short*)(ws + 47196160);  // [768,768]
    short* w1T  = (short*)(ws + 48375808);  // [1536,768]
    short* w2T  = (short*)(ws + 50735104);  // [768,1536], ends 53094400
    short* f1   = (short*)(ws + 0);         // [4096,1536] overlays h1+qkv head (dead)
    short* h2n  = (short*)(ws + 14680064);  // [4096,768] overlays qkv tail (dead)

    prep_kernel<<<5153, 256, 0, stream>>>(wq, wk, wv, wo, w1, w2, vp, up, wpos,
                                          wqkvT, woT, w1T, w2T, sidx, VUg, VSg,
                                          x, n1w, h1);
    gemmx<128><<<dim3(14, 32), 512, 0, stream>>>(h1, wqkvT, nullptr, up, nullptr, qkv, 4096, 1792, 768, 0, 0);
    qv_kernel<<<1024, 256, 0, stream>>>(qkv, wpos, VUg, VSg, Tg, vT, kT);
    flash_kernel<<<dim3(1024), 256, 0, stream>>>(qkv, kT, vT, Tg, sidx, ao);
    gemmx<64><<<dim3(12, 32), 512, 0, stream>>>(ao, woT, bo, nullptr, x, x2, 4096, 768, 768, 0, 1);
    rmsnorm_kernel<<<4096, 256, 0, stream>>>(x2, n2w, h2n);
    gemmx<128><<<dim3(12, 32), 512, 0, stream>>>(h2n, w1T, b1, nullptr, nullptr, f1, 4096, 1536, 768, 1, 0);
    gemmx<64><<<dim3(12, 32), 512, 0, stream>>>(f1, w2T, b2, nullptr, x2, d_out, 4096, 768, 1536, 0, 1);
}